// Round 5
// baseline (227.338 us; speedup 1.0000x reference)
//
#include <hip/hip_runtime.h>

#define B_ 32
#define T_ 2048
#define N_ 128
#define K_ 5
#define BN_ (B_ * N_)
#define PMAX_ 512
#define MINP_ 2

static constexpr double PI_D = 3.14159265358979323846264338327950288;
static constexpr float  S2_F = 0.70710678118654752440f;  // sqrt(1/2)

typedef float vf4 __attribute__((ext_vector_type(4)));

struct cf { float r, i; };

__device__ __forceinline__ void bf_w(cf& u, cf& v, float wr, float wi) {
    const float tr = v.r * wr - v.i * wi;
    const float ti = v.r * wi + v.i * wr;
    v.r = u.r - tr; v.i = u.i - ti;
    u.r += tr;      u.i += ti;
}
__device__ __forceinline__ void bf_1(cf& u, cf& v) {        // w = 1
    const float tr = v.r, ti = v.i;
    v.r = u.r - tr; v.i = u.i - ti;
    u.r += tr;      u.i += ti;
}
__device__ __forceinline__ void bf_mi(cf& u, cf& v) {       // w = -i
    const float tr = v.i, ti = -v.r;
    v.r = u.r - tr; v.i = u.i - ti;
    u.r += tr;      u.i += ti;
}
// LDS bank swizzle: keeps every hot access pattern low-way on 32 banks.
__device__ __forceinline__ int sw(int i) { return i ^ ((i >> 5) & 31); }

// ---------------------------------------------------------------------------
// Kernel 0: twiddle table tw[m] = exp(-2*pi*i*m/2048) as float2, into d_ws.
// ---------------------------------------------------------------------------
__global__ __launch_bounds__(256) void pt_twiddle(float2* __restrict__ tw) {
    const int m = blockIdx.x * 256 + threadIdx.x;
    if (m < 1024) {
        double s, c;
        sincos(-2.0 * PI_D * (double)m / 2048.0, &s, &c);
        tw[m] = make_float2((float)c, (float)s);
    }
}

// ===========================================================================
// Shared device body: FFT + mags + register top-5. Returns with sh_take
// filled and mags dead. Used by both variants via a macro to keep the
// proven code path byte-identical.
// ===========================================================================
#define PT_FFT_BODY()                                                          \
    __syncthreads();                                                           \
    {                                                                          \
        const int base = tid * 8;                                              \
        cf E[8];                                                               \
        _Pragma("unroll")                                                      \
        for (int j = 0; j < 8; ++j) { const int p = sw(base + j); E[j].r = re[p]; E[j].i = im[p]; } \
        bf_1(E[0], E[1]); bf_1(E[2], E[3]); bf_1(E[4], E[5]); bf_1(E[6], E[7]);\
        bf_1(E[0], E[2]); bf_mi(E[1], E[3]); bf_1(E[4], E[6]); bf_mi(E[5], E[7]);\
        bf_1(E[0], E[4]); bf_w(E[1], E[5], S2_F, -S2_F);                       \
        bf_mi(E[2], E[6]); bf_w(E[3], E[7], -S2_F, -S2_F);                     \
        _Pragma("unroll")                                                      \
        for (int j = 0; j < 8; ++j) { const int p = sw(base + j); re[p] = E[j].r; im[p] = E[j].i; } \
    }                                                                          \
    __syncthreads();                                                           \
    _Pragma("unroll")                                                          \
    for (int r = 0; r < 2; ++r) {                                              \
        const int s    = 4 + 3 * r;                                            \
        const int h    = 1 << (s - 1);                                         \
        const int bq   = tid & (h - 1);                                        \
        const int g    = tid >> (s - 1);                                       \
        const int base = g * 8 * h + bq;                                       \
        const float2 w1  = tw[bq << (11 - s)];                                 \
        const float2 w2a = tw[bq << (10 - s)];                                 \
        const float2 w2b = tw[(bq + h) << (10 - s)];                           \
        const float2 w30 = tw[bq << (9 - s)];                                  \
        const float2 w31 = tw[(bq + h) << (9 - s)];                            \
        const float2 w32 = tw[(bq + 2 * h) << (9 - s)];                        \
        const float2 w33 = tw[(bq + 3 * h) << (9 - s)];                        \
        cf E[8];                                                               \
        _Pragma("unroll")                                                      \
        for (int j = 0; j < 8; ++j) { const int p = sw(base + j * h); E[j].r = re[p]; E[j].i = im[p]; } \
        bf_w(E[0], E[1], w1.x, w1.y);   bf_w(E[2], E[3], w1.x, w1.y);          \
        bf_w(E[4], E[5], w1.x, w1.y);   bf_w(E[6], E[7], w1.x, w1.y);          \
        bf_w(E[0], E[2], w2a.x, w2a.y); bf_w(E[1], E[3], w2b.x, w2b.y);        \
        bf_w(E[4], E[6], w2a.x, w2a.y); bf_w(E[5], E[7], w2b.x, w2b.y);        \
        bf_w(E[0], E[4], w30.x, w30.y); bf_w(E[1], E[5], w31.x, w31.y);        \
        bf_w(E[2], E[6], w32.x, w32.y); bf_w(E[3], E[7], w33.x, w33.y);        \
        _Pragma("unroll")                                                      \
        for (int j = 0; j < 8; ++j) { const int p = sw(base + j * h); re[p] = E[j].r; im[p] = E[j].i; } \
        __syncthreads();                                                       \
    }                                                                          \
    _Pragma("unroll")                                                          \
    for (int u = 0; u < 2; ++u) {                                              \
        const int bb = tid + 256 * u;                                          \
        const float2 wA = tw[bb << 1];                                         \
        const float2 wB = tw[bb];                                              \
        const float2 wC = tw[bb + 512];                                        \
        const int p0 = sw(bb), p1 = sw(bb + 512), p2 = sw(bb + 1024), p3 = sw(bb + 1536); \
        cf E0 = {re[p0], im[p0]}, E1 = {re[p1], im[p1]};                       \
        cf E2 = {re[p2], im[p2]}, E3 = {re[p3], im[p3]};                       \
        bf_w(E0, E1, wA.x, wA.y); bf_w(E2, E3, wA.x, wA.y);                    \
        bf_w(E0, E2, wB.x, wB.y); bf_w(E1, E3, wC.x, wC.y);                    \
        re[p0] = E0.r; im[p0] = E0.i; re[p1] = E1.r; im[p1] = E1.i;            \
        re[p2] = E2.r; im[p2] = E2.i; re[p3] = E3.r; im[p3] = E3.i;            \
    }                                                                          \
    __syncthreads();                                                           \
    float magsA[4], magsB[4];                                                  \
    _Pragma("unroll")                                                          \
    for (int m = 0; m < 4; ++m) {                                              \
        const int k  = 1 + tid + 256 * m;                                      \
        const int nk = 2048 - k;                                               \
        const int pk = sw(k), pn = sw(nk);                                     \
        const float zr = re[pk], zi = im[pk];                                  \
        const float yr = re[pn], yi = im[pn];                                  \
        const float ar = zr + yr, ai = zi - yi;                                \
        const float br = zi + yi, bi = yr - zr;                                \
        magsA[m] = ar * ar + ai * ai;                                          \
        magsB[m] = br * br + bi * bi;                                          \
    }                                                                          \
    __syncthreads();                                                           \
    _Pragma("unroll")                                                          \
    for (int m = 0; m < 4; ++m) {                                              \
        const int pk = sw(1 + tid + 256 * m);                                  \
        re[pk] = magsA[m];                                                     \
        im[pk] = magsB[m];                                                     \
    }                                                                          \
    __syncthreads();                                                           \
    const int wid  = tid >> 6;                                                 \
    const int lane = tid & 63;                                                 \
    if (wid < 2) {                                                             \
        const float* marr = wid ? im : re;                                     \
        float mv[16];                                                          \
        _Pragma("unroll")                                                      \
        for (int j = 0; j < 16; ++j) mv[j] = marr[sw(1 + lane + 64 * j)];      \
        for (int it = 0; it < K_; ++it) {                                      \
            float bestv = -2.0f;                                               \
            int   besti = 1 << 30;                                             \
            _Pragma("unroll")                                                  \
            for (int j = 0; j < 16; ++j) {                                     \
                const int k = 1 + lane + 64 * j;                               \
                if (mv[j] > bestv || (mv[j] == bestv && k < besti)) { bestv = mv[j]; besti = k; } \
            }                                                                  \
            _Pragma("unroll")                                                  \
            for (int off = 32; off > 0; off >>= 1) {                           \
                const float v3 = __shfl_down(bestv, off);                      \
                const int   i3 = __shfl_down(besti, off);                      \
                if (v3 > bestv || (v3 == bestv && i3 < besti)) { bestv = v3; besti = i3; } \
            }                                                                  \
            const int win = __shfl(besti, 0);                                  \
            _Pragma("unroll")                                                  \
            for (int j = 0; j < 16; ++j)                                       \
                if (1 + lane + 64 * j == win) mv[j] = -1.0f;                   \
            if (lane == 0) {                                                   \
                int period = T_ / win;                                         \
                if (period > PMAX_) period = PMAX_;                            \
                if (period < MINP_) period = MINP_;                            \
                const int cyc = T_ / period;                                   \
                sh_take[wid][it] = (period << 16) | (period * cyc);            \
            }                                                                  \
        }                                                                      \
    }                                                                          \
    __syncthreads();

// ---------------------------------------------------------------------------
// v5: seq carried in WORKSPACE (not registers, not LDS).
//  - After the uncoalesced x load, seq is written coalesced to ws[bn][t]
//    (fire-and-forget; drained by the first FFT barrier). v[] dies -> VGPR
//    drops below 64 -> 8 blocks/CU (32 waves, occupancy max).
//  - Store phase reads ws rows (L3-resident within the iteration) with
//    aligned float4 pairs + register shift; LDS not touched after top-5,
//    seq-restore pass + barrier gone.
// ---------------------------------------------------------------------------
__global__ __launch_bounds__(256, 8) void pt_fft_tiles_ws(const float* __restrict__ x,
                                                          float* __restrict__ out,
                                                          const float2* __restrict__ tw,
                                                          float* __restrict__ seqws) {
    __shared__ float re[2048];
    __shared__ float im[2048];
    __shared__ int sh_take[2][K_];

    const int i0  = blockIdx.x;
    const int q   = ((i0 & 7) << 8) | (i0 >> 3);
    const int bn0 = q * 2;
    const int b   = bn0 >> 7;          // / N_
    const int n   = bn0 & 127;         // even
    const int tid = threadIdx.x;

    float* wsA = seqws + (size_t)bn0 * T_;
    float* wsB = wsA + T_;

    // ---- Load x columns (n, n+1): bit-reversed pack into re/im + coalesced
    // seq spill to workspace (dword streams; drained at first barrier).
    const float* xp = x + (size_t)b * T_ * N_ + n;
    {
        float2 v[8];
#pragma unroll
        for (int m = 0; m < 8; ++m)
            v[m] = *(const float2*)(xp + (size_t)(tid + 256 * m) * N_);
#pragma unroll
        for (int m = 0; m < 8; ++m) {
            const int t = tid + 256 * m;
            const int p = sw((int)(__brev((unsigned)t) >> 21));   // pos = rev11(t)
            re[p] = v[m].x;
            im[p] = v[m].y;
            wsA[t] = v[m].x;
            wsB[t] = v[m].y;
        }
    }

    PT_FFT_BODY()

    // ---- periods / cycles (ints as float32).
    const size_t TILES = (size_t)BN_ * K_ * T_;
    if (tid < 2 * K_) {
        const int s2 = tid / K_, k2 = tid % K_;
        const int pk   = sh_take[s2][k2];
        const int per  = pk >> 16;
        const int take = pk & 0xFFFF;
        out[TILES + (size_t)(bn0 + s2) * K_ + k2]                      = (float)per;
        out[TILES + (size_t)BN_ * K_ + (size_t)(bn0 + s2) * K_ + k2]   = (float)(take / per);
    }

    // ---- Tile rows: aligned f4 reads FROM WORKSPACE (L3) + register shift,
    // regular aligned float4 stores.
    float* rowA = out + (size_t)bn0 * (K_ * T_);
#pragma unroll
    for (int m = 0; m < 20; ++m) {
        const int e  = tid + 256 * m;
        const int s2 = (e >= K_ * (T_ / 4)) ? 1 : 0;
        const int w  = e - s2 * (K_ * (T_ / 4));
        const int k  = w >> 9;                     // / 512
        const int p4 = (w & 511) << 2;
        const int take  = sh_take[s2][k] & 0xFFFF;
        const int start = T_ - take;
        const vf4* sq4 = (const vf4*)(s2 ? wsB : wsA);
        const int idx = start + p4;
        int a0 = idx >> 2;
        if (a0 > 511) a0 = 511;                    // clamp (masked anyway)
        const int sh = idx & 3;
        const vf4 lo = sq4[a0];
        const vf4 hi = sq4[a0 + 1];                // <=512: 16B slack in ws
        float r0, r1, r2, r3;
        if (sh == 0)      { r0 = lo.x; r1 = lo.y; r2 = lo.z; r3 = lo.w; }
        else if (sh == 1) { r0 = lo.y; r1 = lo.z; r2 = lo.w; r3 = hi.x; }
        else if (sh == 2) { r0 = lo.z; r1 = lo.w; r2 = hi.x; r3 = hi.y; }
        else              { r0 = lo.w; r1 = hi.x; r2 = hi.y; r3 = hi.z; }
        vf4 vv;
        vv.x = (p4 + 0 < take) ? r0 : 0.0f;
        vv.y = (p4 + 1 < take) ? r1 : 0.0f;
        vv.z = (p4 + 2 < take) ? r2 : 0.0f;
        vv.w = (p4 + 3 < take) ? r3 : 0.0f;
        *(vf4*)(rowA + (size_t)(s2 * K_ + k) * T_ + p4) = vv;
    }
}

// ---------------------------------------------------------------------------
// v4 fallback (proven, R4): seq carried in registers, restored to LDS.
// Used when ws_size can't hold the 33.6 MB sequence buffer.
// ---------------------------------------------------------------------------
__global__ __launch_bounds__(256, 7) void pt_fft_tiles_reg(const float* __restrict__ x,
                                                           float* __restrict__ out,
                                                           const float2* __restrict__ tw) {
    __shared__ __align__(16) float re[2052];
    __shared__ __align__(16) float im[2052];
    __shared__ int sh_take[2][K_];

    const int i0  = blockIdx.x;
    const int q   = ((i0 & 7) << 8) | (i0 >> 3);
    const int bn0 = q * 2;
    const int b   = bn0 >> 7;
    const int n   = bn0 & 127;
    const int tid = threadIdx.x;

    const float* xp = x + (size_t)b * T_ * N_ + n;
    float2 v[8];
#pragma unroll
    for (int m = 0; m < 8; ++m)
        v[m] = *(const float2*)(xp + (size_t)(tid + 256 * m) * N_);
#pragma unroll
    for (int m = 0; m < 8; ++m) {
        const int t = tid + 256 * m;
        const int p = sw((int)(__brev((unsigned)t) >> 21));
        re[p] = v[m].x;
        im[p] = v[m].y;
    }

    PT_FFT_BODY()

    const size_t TILES = (size_t)BN_ * K_ * T_;
    if (tid < 2 * K_) {
        const int s2 = tid / K_, k2 = tid % K_;
        const int pk   = sh_take[s2][k2];
        const int per  = pk >> 16;
        const int take = pk & 0xFFFF;
        out[TILES + (size_t)(bn0 + s2) * K_ + k2]                      = (float)per;
        out[TILES + (size_t)BN_ * K_ + (size_t)(bn0 + s2) * K_ + k2]   = (float)(take / per);
    }

#pragma unroll
    for (int m = 0; m < 8; ++m) {
        const int t = tid + 256 * m;
        re[t] = v[m].x;
        im[t] = v[m].y;
    }
    __syncthreads();

    float* rowA = out + (size_t)bn0 * (K_ * T_);
#pragma unroll
    for (int m = 0; m < 20; ++m) {
        const int e  = tid + 256 * m;
        const int s2 = (e >= K_ * (T_ / 4)) ? 1 : 0;
        const int w  = e - s2 * (K_ * (T_ / 4));
        const int k  = w >> 9;
        const int p4 = (w & 511) << 2;
        const int take  = sh_take[s2][k] & 0xFFFF;
        const int start = T_ - take;
        const vf4* sq4 = (const vf4*)(s2 ? im : re);
        const int idx = start + p4;
        int a0 = idx >> 2;
        if (a0 > 511) a0 = 511;
        const int sh = idx & 3;
        const vf4 lo = sq4[a0];
        const vf4 hi = sq4[a0 + 1];
        float r0, r1, r2, r3;
        if (sh == 0)      { r0 = lo.x; r1 = lo.y; r2 = lo.z; r3 = lo.w; }
        else if (sh == 1) { r0 = lo.y; r1 = lo.z; r2 = lo.w; r3 = hi.x; }
        else if (sh == 2) { r0 = lo.z; r1 = lo.w; r2 = hi.x; r3 = hi.y; }
        else              { r0 = lo.w; r1 = hi.x; r2 = hi.y; r3 = hi.z; }
        vf4 vv;
        vv.x = (p4 + 0 < take) ? r0 : 0.0f;
        vv.y = (p4 + 1 < take) ? r1 : 0.0f;
        vv.z = (p4 + 2 < take) ? r2 : 0.0f;
        vv.w = (p4 + 3 < take) ? r3 : 0.0f;
        *(vf4*)(rowA + (size_t)(s2 * K_ + k) * T_ + p4) = vv;
    }
}

// ---------------------------------------------------------------------------
extern "C" void kernel_launch(void* const* d_in, const int* in_sizes, int n_in,
                              void* d_out, int out_size, void* d_ws, size_t ws_size,
                              hipStream_t stream) {
    const float* x = (const float*)d_in[0];
    float* out = (float*)d_out;
    float2* tw = (float2*)d_ws;                            // 8 KB twiddle table
    float* seqws = (float*)((char*)d_ws + 8192);           // 33.6 MB seq buffer

    const size_t ws_need = 8192 + ((size_t)BN_ * T_ + 4) * sizeof(float);

    pt_twiddle<<<dim3(4), dim3(256), 0, stream>>>(tw);
    if (ws_size >= ws_need) {
        pt_fft_tiles_ws<<<dim3(BN_ / 2), dim3(256), 0, stream>>>(x, out, tw, seqws);
    } else {
        pt_fft_tiles_reg<<<dim3(BN_ / 2), dim3(256), 0, stream>>>(x, out, tw);
    }
}

// Round 7
// 224.477 us; speedup vs baseline: 1.0127x; 1.0127x over previous
//
#include <hip/hip_runtime.h>

#define B_ 32
#define T_ 2048
#define N_ 128
#define K_ 5
#define BN_ (B_ * N_)
#define PMAX_ 512
#define MINP_ 2

static constexpr double PI_D = 3.14159265358979323846264338327950288;

typedef float vf4 __attribute__((ext_vector_type(4)));

struct cf { float r, i; };

__device__ __forceinline__ void bf_w(cf& u, cf& v, float wr, float wi) {
    const float tr = v.r * wr - v.i * wi;
    const float ti = v.r * wi + v.i * wr;
    v.r = u.r - tr; v.i = u.i - ti;
    u.r += tr;      u.i += ti;
}
__device__ __forceinline__ void bf_1(cf& u, cf& v) {        // w = 1
    const float tr = v.r, ti = v.i;
    v.r = u.r - tr; v.i = u.i - ti;
    u.r += tr;      u.i += ti;
}
__device__ __forceinline__ void bf_mi(cf& u, cf& v) {       // w = -i
    const float tr = v.i, ti = -v.r;
    v.r = u.r - tr; v.i = u.i - ti;
    u.r += tr;      u.i += ti;
}
// LDS bank swizzle: keeps every hot access pattern low-way on 32 banks.
__device__ __forceinline__ int sw(int i) { return i ^ ((i >> 5) & 31); }

// ---------------------------------------------------------------------------
// Kernel 0: twiddle table tw[m] = exp(-2*pi*i*m/2048) as float2, into d_ws.
// ---------------------------------------------------------------------------
__global__ __launch_bounds__(256) void pt_twiddle(float2* __restrict__ tw) {
    const int m = blockIdx.x * 256 + threadIdx.x;
    if (m < 1024) {
        double s, c;
        sincos(-2.0 * PI_D * (double)m / 2048.0, &s, &c);
        tw[m] = make_float2((float)c, (float)s);
    }
}

// ---------------------------------------------------------------------------
// v7 = v6 with the XCD swizzle fixed for a 4096-block grid.
// ONE series per block -> 4096 blocks = 8 blocks/CU.
// Real 2048-pt rFFT via 1024-pt complex FFT (z[m]=s[2m]+i*s[2m+1]) + untangle:
//   S[k]   = Fe[k] + W^k * Fo[k],  W = e^{-2pi i/2048}
//   2*Fe   = Z[k] + conj(Z[1024-k]);  2i*Fo = Z[k] - conj(Z[1024-k])
//   mag2(2S[k]) ranks identically to mag2(S[k]) (uniform x4 scale).
// Radix-4 x5 rounds (all 256 threads busy on 1024 points).
// LDS: L[2056] (RE/IM during FFT, then seq[0:2048]) + M[1028] mags
//   -> mags live separately so waves 1-3 restore seq WHILE wave 0 top-5s.
// Seq carried in 8 VGPR. Store phase: proven shifted-f4 + masked f4 stores.
// ---------------------------------------------------------------------------
__global__ __launch_bounds__(256, 8) void pt_fft_tiles(const float* __restrict__ x,
                                                       float* __restrict__ out,
                                                       const float2* __restrict__ tw) {
    __shared__ __align__(16) float L[2056];  // RE=L[sw(i)], IM=L[1028+sw(i)]; later seq
    __shared__ float M[1028];                // mags: k=1..1024 at M[sw(k-1)]
    __shared__ int sh_take[K_];

    // XCD-aware swizzle, BIJECTIVE on [0,4096): a = i0&7 (bits 9-11),
    // c = i0>>3 in [0,512) (bits 0-8). Blocks sharing (i0&7) (likely same
    // XCD) get consecutive bn -> adjacent x columns -> L2 line reuse.
    const int i0  = blockIdx.x;
    const int bn  = ((i0 & 7) << 9) | (i0 >> 3);
    const int b   = bn >> 7;           // / N_
    const int n   = bn & 127;
    const int tid = threadIdx.x;

    // ---- Load one column: z[m] = s[2m] + i*s[2m+1], bit-reversed (10-bit).
    // sv[] (8 floats) carries the sequence to the store phase.
    const float* xp = x + (size_t)b * T_ * N_ + n;
    float2 sv[4];
#pragma unroll
    for (int m = 0; m < 4; ++m) {
        const int mm = tid + 256 * m;
        sv[m].x = xp[(size_t)(2 * mm) * N_];
        sv[m].y = xp[(size_t)(2 * mm + 1) * N_];
        const int p = sw((int)(__brev((unsigned)mm) >> 22));   // rev10(mm)
        L[p]        = sv[m].x;
        L[1028 + p] = sv[m].y;
    }
    __syncthreads();

    // ---- Round 0: radix-4 (stages 1-2), h=1, constant twiddles.
    {
        const int base = tid * 4;
        cf E[4];
#pragma unroll
        for (int j = 0; j < 4; ++j) { const int p = sw(base + j); E[j].r = L[p]; E[j].i = L[1028 + p]; }
        bf_1(E[0], E[1]); bf_1(E[2], E[3]);
        bf_1(E[0], E[2]); bf_mi(E[1], E[3]);
#pragma unroll
        for (int j = 0; j < 4; ++j) { const int p = sw(base + j); L[p] = E[j].r; L[1028 + p] = E[j].i; }
    }
    __syncthreads();

    // ---- Rounds 1..4: radix-4 at h = 4^r (stages 3-4, 5-6, 7-8, 9-10).
#pragma unroll
    for (int r = 1; r < 5; ++r) {
        const int h    = 1 << (2 * r);
        const int bq   = tid & (h - 1);
        const int g    = tid >> (2 * r);
        const int base = g * 4 * h + bq;
        const float2 w1  = tw[bq << (10 - 2 * r)];        // e^{-2pi i bq/(2h)}
        const float2 w2a = tw[bq << (9 - 2 * r)];         // e^{-2pi i bq/(4h)}
        const float2 w2b = tw[(bq + h) << (9 - 2 * r)];   // e^{-2pi i (bq+h)/(4h)}
        cf E[4];
#pragma unroll
        for (int j = 0; j < 4; ++j) { const int p = sw(base + j * h); E[j].r = L[p]; E[j].i = L[1028 + p]; }
        bf_w(E[0], E[1], w1.x, w1.y);   bf_w(E[2], E[3], w1.x, w1.y);
        bf_w(E[0], E[2], w2a.x, w2a.y); bf_w(E[1], E[3], w2b.x, w2b.y);
#pragma unroll
        for (int j = 0; j < 4; ++j) { const int p = sw(base + j * h); L[p] = E[j].r; L[1028 + p] = E[j].i; }
        __syncthreads();
    }

    // ---- Untangle + 4*mag^2 straight into M (disjoint from L: no barrier
    // needed between the L-reads and M-writes).
#pragma unroll
    for (int m = 0; m < 4; ++m) {
        const int k = 1 + tid + 256 * m;                  // 1..1024
        float mg;
        if (k == 1024) {
            const int p0 = sw(0);
            const float d = L[p0] - L[1028 + p0];         // Re(Z0) - Im(Z0)
            mg = 4.0f * d * d;
        } else {
            const int pk = sw(k), pn = sw(1024 - k);
            const float zr = L[pk],  zi = L[1028 + pk];
            const float yr = L[pn],  yi = L[1028 + pn];
            const float Ar = zr + yr, Ai = zi - yi;       // 2*Fe
            const float Br = zr - yr, Bi = zi + yi;       // 2i*Fo
            const float2 w = tw[k];
            const float Cr = w.x * Bi + w.y * Br;         // W^k * (-i*B)
            const float Ci = w.y * Bi - w.x * Br;
            const float sr = Ar + Cr, si = Ai + Ci;       // 2*S[k]
            mg = sr * sr + si * si;
        }
        M[sw(k - 1)] = mg;
    }
    __syncthreads();

    // ---- Wave 0: register top-5 over M (16 bins/lane, zero barriers).
    // Waves 1-3 proceed straight to seq restore (L is dead, M untouched).
    const int wid  = tid >> 6;
    const int lane = tid & 63;
    if (wid == 0) {
        float mv[16];
#pragma unroll
        for (int j = 0; j < 16; ++j) mv[j] = M[sw(lane + 64 * j)];
        for (int it = 0; it < K_; ++it) {
            float bestv = -2.0f;
            int   besti = 1 << 30;
#pragma unroll
            for (int j = 0; j < 16; ++j) {
                const int k = 1 + lane + 64 * j;
                if (mv[j] > bestv || (mv[j] == bestv && k < besti)) { bestv = mv[j]; besti = k; }
            }
#pragma unroll
            for (int off = 32; off > 0; off >>= 1) {
                const float v3 = __shfl_down(bestv, off);
                const int   i3 = __shfl_down(besti, off);
                if (v3 > bestv || (v3 == bestv && i3 < besti)) { bestv = v3; besti = i3; }
            }
            const int win = __shfl(besti, 0);      // broadcast winner index
#pragma unroll
            for (int j = 0; j < 16; ++j)
                if (1 + lane + 64 * j == win) mv[j] = -1.0f;   // exclude
            if (lane == 0) {
                int period = T_ / win;
                if (period > PMAX_) period = PMAX_;
                if (period < MINP_) period = MINP_;
                const int cyc = T_ / period;
                sh_take[it] = (period << 16) | (period * cyc); // pack period|take
            }
        }
    }

    // ---- Restore sequence linearly into L[0:2048] from registers.
#pragma unroll
    for (int m = 0; m < 4; ++m) {
        const int mm = tid + 256 * m;
        *(float2*)(L + 2 * mm) = sv[m];
    }
    __syncthreads();

    // ---- periods / cycles (ints as float32).
    const size_t TILES = (size_t)BN_ * K_ * T_;
    if (tid < K_) {
        const int pk   = sh_take[tid];
        const int per  = pk >> 16;
        const int take = pk & 0xFFFF;
        out[TILES + (size_t)bn * K_ + tid]                      = (float)per;
        out[TILES + (size_t)BN_ * K_ + (size_t)bn * K_ + tid]   = (float)(take / per);
    }

    // ---- Tile rows: aligned f4 LDS reads + register shift, REGULAR aligned
    // float4 stores (same shape as the 6.5 TB/s fill kernel). 10 iters.
    float* row = out + (size_t)bn * (K_ * T_);
    const vf4* L4 = (const vf4*)L;
#pragma unroll
    for (int m = 0; m < 10; ++m) {
        const int e  = tid + 256 * m;
        const int k  = e >> 9;                     // / 512
        const int p4 = (e & 511) << 2;
        const int take  = sh_take[k] & 0xFFFF;
        const int start = T_ - take;
        const int idx = start + p4;
        int a0 = idx >> 2;
        if (a0 > 511) a0 = 511;                    // clamp (masked anyway)
        const int sh = idx & 3;
        const vf4 lo = L4[a0];
        const vf4 hi = L4[a0 + 1];                 // <= L[2051], within L[2056]
        float r0, r1, r2, r3;
        if (sh == 0)      { r0 = lo.x; r1 = lo.y; r2 = lo.z; r3 = lo.w; }
        else if (sh == 1) { r0 = lo.y; r1 = lo.z; r2 = lo.w; r3 = hi.x; }
        else if (sh == 2) { r0 = lo.z; r1 = lo.w; r2 = hi.x; r3 = hi.y; }
        else              { r0 = lo.w; r1 = hi.x; r2 = hi.y; r3 = hi.z; }
        vf4 vv;
        vv.x = (p4 + 0 < take) ? r0 : 0.0f;
        vv.y = (p4 + 1 < take) ? r1 : 0.0f;
        vv.z = (p4 + 2 < take) ? r2 : 0.0f;
        vv.w = (p4 + 3 < take) ? r3 : 0.0f;
        *(vf4*)(row + (size_t)k * T_ + p4) = vv;
    }
}

// ---------------------------------------------------------------------------
extern "C" void kernel_launch(void* const* d_in, const int* in_sizes, int n_in,
                              void* d_out, int out_size, void* d_ws, size_t ws_size,
                              hipStream_t stream) {
    const float* x = (const float*)d_in[0];
    float* out = (float*)d_out;
    float2* tw = (float2*)d_ws;   // 8 KB twiddle table

    pt_twiddle<<<dim3(4), dim3(256), 0, stream>>>(tw);
    pt_fft_tiles<<<dim3(BN_), dim3(256), 0, stream>>>(x, out, tw);
}